// Round 5
// baseline (496.805 us; speedup 1.0000x reference)
//
#include <hip/hip_runtime.h>
#include <math.h>

#define HID 128
#define NN 512
#define NNODE 1024
#define CUTR 10.0f
#define JSPLIT 4                 // blocks per node; each handles 128 j's

// ---- ws layout, float offsets
#define WS_A    0                // [1024][256] fp32  (A_i + bias + const-angular row)
#define WS_BMF  262144           // BmT fp32 [2][256][512] (c-major, j inner)
#define WS_MSG4 524288           // [1024][4][128] fp32 partial msg
#define WS_UPD  1048576          // [1024][4][4] fp32 partial (S,SX,SY,-)
// ---- ws layout, ushort offsets (floats end at 1064960 -> ushort 2129920)
#define SE2T_OFF 2129920         // ew2^T bf16 [128][256]
#define SC1T_OFF (SE2T_OFF + 32768)   // cw1^T bf16 [128][128]
#define SW1G_OFF (SC1T_OFF + 16384)   // W1g^T bf16 [256][16]

// ---- out layout (float offsets)
#define OUT_POS 131072
#define OUT_VEL 133120

typedef __attribute__((ext_vector_type(8)))  short short8;
typedef __attribute__((ext_vector_type(8)))  __bf16 bf16x8;
typedef __attribute__((ext_vector_type(16))) float float16;

__device__ __forceinline__ float silu_f(float x) {
  // x * rcp(1+exp(-x)): v_rcp_f32 instead of the IEEE div sequence
  return x * __builtin_amdgcn_rcpf(1.f + __expf(-x));
}
__device__ __forceinline__ short f2bf(float x) {
  return __builtin_bit_cast(short, (__bf16)x);   // native cvt on gfx950
}
__device__ __forceinline__ bf16x8 as_bf(short8 s) {
  return __builtin_bit_cast(bf16x8, s);
}
__device__ __forceinline__ float16 zero16() {
  float16 z;
#pragma unroll
  for (int r = 0; r < 16; ++r) z[r] = 0.f;
  return z;
}

// ---------------------------------------------------------------- K0
// Transpose + bf16-convert weights: ew2^T, cw1^T, W1g^T (geometry rows of ew1).
__global__ __launch_bounds__(256)
void k0_prep(const float* __restrict__ ew1, const float* __restrict__ ew2,
             const float* __restrict__ cw1, unsigned short* __restrict__ wsU) {
  int idx = blockIdx.x * 256 + threadIdx.x;
  if (idx < 32768) {
    int c = idx >> 8, k = idx & 255;
    wsU[SE2T_OFF + c*256 + k] = (unsigned short)f2bf(ew2[k*HID + c]);
  } else if (idx < 49152) {
    int i2 = idx - 32768; int c = i2 >> 7, k = i2 & 127;
    wsU[SC1T_OFF + c*128 + k] = (unsigned short)f2bf(cw1[k*HID + c]);
  } else if (idx < 53248) {
    int i3 = idx - 49152; int c = i3 >> 4, f = i3 & 15;
    // f: 0..7 radial -> ew1 rows 256..263; 8..11 cos -> 265..268; 12..15 sin -> 269..272
    int row = (f < 8) ? (256 + f) : (257 + f);
    wsU[SW1G_OFF + c*16 + f] = (unsigned short)f2bf(ew1[row*256 + c]);
  }
}

// ---------------------------------------------------------------- K1
// A[n][c] = eb1[c] + ew1[264][c] + sum_k h[n][k]*ew1[k][c]   (fp32, [node][256])
// BmT[b][c][j] = fp32 sum_k h[b,j][k]*ew1[128+k][c]          (c-major for float4 C-init)
__global__ __launch_bounds__(256)
void k1_precompute(const float* __restrict__ h, const float* __restrict__ ew1,
                   const float* __restrict__ eb1, float* __restrict__ ws) {
  int node = blockIdx.x;
  int c = threadIdx.x;
  __shared__ float sh_h[HID];
  if (c < HID) sh_h[c] = h[node*HID + c];
  __syncthreads();
  float a  = eb1[c] + ew1[264*256 + c];
  float bm = 0.f;
#pragma unroll 4
  for (int k = 0; k < HID; ++k) {
    float hv = sh_h[k];
    a  += hv * ew1[k*256 + c];
    bm += hv * ew1[(128+k)*256 + c];
  }
  ws[WS_A + node*256 + c] = a;
  int b = node >> 9, j = node & 511;
  ws[WS_BMF + b*131072 + c*512 + j] = bm;
}

// ---------------------------------------------------------------- K3
// JSPLIT blocks per node; block (node,part) handles j in [part*128, part*128+128).
// 4 waves; wave w owns output cols [32w,32w+32). Partial msg/upd -> ws; k4 merges.
__global__ __launch_bounds__(256)
void k3_edge(const float* __restrict__ pos,
             const float* __restrict__ eb2, const float* __restrict__ cb1,
             const float* __restrict__ cw2, const float* __restrict__ cb2,
             float* __restrict__ ws) {
  const short* wsS = (const short*)ws;
  __shared__ __align__(16) short shH[32*256];   // bf16, xor-swizzled 16B chunks
  __shared__ __align__(16) short shE[32*128];   // bf16, xor-swizzled 16B chunks
  __shared__ float shred[12];

  const int t = threadIdx.x;
  const int w = t >> 6, l = t & 63, lo = l & 31, hl = l >> 5, hl4 = hl * 4;
  const int node = blockIdx.x >> 2;
  const int part = blockIdx.x & 3;
  const int b = node >> 9;
  const int bN = b * NN;
  const int jb0 = part * 128;

  // persistent B-fragments: cw1^T (8 MFMA steps, reused 4x) + W1g^T (2 halves)
  bf16x8 wb2[8];
  {
    const short* p = wsS + SC1T_OFF + (32*w + lo)*128 + hl*8;
#pragma unroll
    for (int s = 0; s < 8; ++s) wb2[s] = as_bf(*(const short8*)(p + s*16));
  }
  const bf16x8 wg0 = as_bf(*(const short8*)(wsS + SW1G_OFF + (64*w + lo)*16 + hl*8));
  const bf16x8 wg1 = as_bf(*(const short8*)(wsS + SW1G_OFF + (64*w + 32 + lo)*16 + hl*8));

  const float a0   = ws[WS_A + node*256 + 64*w + lo];
  const float a1   = ws[WS_A + node*256 + 64*w + 32 + lo];
  const float ebv  = eb2[32*w + lo];
  const float cb1v = cb1[32*w + lo];
  const float c2v  = cw2[32*w + lo];
  const float cb2c = cb2[0] * (1.f/128.f);
  const float pix  = pos[node*2], piy = pos[node*2+1];

  float msum = 0.f;
  float S = 0.f, SX = 0.f, SY = 0.f;

  for (int jb = jb0; jb < jb0 + 128; jb += 32) {
    // ---- inline geometry for j = jb + lo
    const int jn = bN + jb + lo;
    const float pjx = pos[2*jn], pjy = pos[2*jn+1];
    const float dx = pix - pjx, dy = piy - pjy;
    const float d = sqrtf(dx*dx + dy*dy);
    const float cutv = (d < CUTR) ? 0.5f*(__cosf((float)M_PI*(1.f/CUTR)*d) + 1.f) : 0.f;
    short8 gs;
    if (hl == 0) {
      // radial features 0..7
#pragma unroll
      for (int k = 0; k < 8; ++k) {
        float ctr = (CUTR * (float)k) / 7.0f;
        float tt = (d - ctr) * 0.8f;
        gs[k] = f2bf(__expf(-tt*tt));
      }
    } else {
      // angular features: cos(m th), sin(m th) via recurrence on (dx/d, dy/d)
      float invd = __builtin_amdgcn_rcpf(d + 1e-8f);
      float c1 = dx * invd, s1 = dy * invd;
      if (d == 0.f) { c1 = 1.f; s1 = 0.f; }   // matches atan2(0,0)=0
      float c2 = c1*c1 - s1*s1, s2 = 2.f*s1*c1;
      float c3 = c2*c1 - s2*s1, s3 = s2*c1 + c2*s1;
      float c4 = c3*c1 - s3*s1, s4 = s3*c1 + c3*s1;
      gs[0]=f2bf(c1); gs[1]=f2bf(c2); gs[2]=f2bf(c3); gs[3]=f2bf(c4);
      gs[4]=f2bf(s1); gs[5]=f2bf(s2); gs[6]=f2bf(s3); gs[7]=f2bf(s4);
    }
    const bf16x8 gf = as_bf(gs);

    // ---- phase 1: Hpre = G @ W1g + (A_i + Bm_j); silu -> shH (bf16, swizzled)
#pragma unroll
    for (int ct = 0; ct < 2; ++ct) {
      const int colg = 64*w + 32*ct + lo;
      const float av = ct ? a1 : a0;
      const float* bt = ws + WS_BMF + b*131072 + colg*512 + jb + hl4;
      float16 ci;
#pragma unroll
      for (int g = 0; g < 4; ++g) {
        float4 v4 = *(const float4*)(bt + 8*g);
        ci[4*g+0] = v4.x + av;
        ci[4*g+1] = v4.y + av;
        ci[4*g+2] = v4.z + av;
        ci[4*g+3] = v4.w + av;
      }
      float16 hp = __builtin_amdgcn_mfma_f32_32x32x16_bf16(gf, ct ? wg1 : wg0, ci, 0, 0, 0);
      const int ck = colg >> 3;
#pragma unroll
      for (int r = 0; r < 16; ++r) {
        int row = (r&3) + 8*(r>>2) + hl4;
        shH[row*256 + (((ck ^ row) & 31) << 3) + (colg & 7)] = f2bf(silu_f(hp[r]));
      }
    }
    __syncthreads();

    // ---- GEMM1: e = H @ ew2 (K=256), weights streamed from L1/L2.
    float16 acc1 = zero16();
    {
      const short* wp1 = wsS + SE2T_OFF + (32*w + lo)*256 + hl*8;
#pragma unroll 4
      for (int s = 0; s < 16; ++s) {
        bf16x8 wv = as_bf(*(const short8*)(wp1 + 16*s));
        const int ck = 2*s + hl;
        bf16x8 af = as_bf(*(const short8*)(shH + lo*256 + (((ck ^ lo) & 31) << 3)));
        acc1 = __builtin_amdgcn_mfma_f32_32x32x16_bf16(af, wv, acc1, 0, 0, 0);
      }
    }
    // epilogue 1: +bias, *cutoff (shfl), msg acc, bf16 -> shE
    const int kE = 32*w + lo;
    const int ckE = kE >> 3;
#pragma unroll
    for (int r = 0; r < 16; ++r) {
      int row = (r&3) + 8*(r>>2) + hl4;
      float cr = __shfl(cutv, row, 32);
      float ev = (acc1[r] + ebv) * cr;
      msum += ev;
      shE[row*128 + (((ckE ^ (row & 15)) & 15) << 3) + (kE & 7)] = f2bf(ev);
    }
    __syncthreads();

    // ---- GEMM2: c1 = E @ cw1 (K=128)
    float16 acc2 = zero16();
#pragma unroll
    for (int s = 0; s < 8; ++s) {
      const int ck = 2*s + hl;
      bf16x8 af = as_bf(*(const short8*)(shE + lo*128 + (((ck ^ (lo & 15)) & 15) << 3)));
      acc2 = __builtin_amdgcn_mfma_f32_32x32x16_bf16(af, wb2[s], acc2, 0, 0, 0);
    }
    // epilogue 2: silu, *cw2, accumulate S / SX / SY (upd = pos_i*S - S*pos_j)
#pragma unroll
    for (int r = 0; r < 16; ++r) {
      int row = (r&3) + 8*(r>>2) + hl4;
      float p = silu_f(acc2[r] + cb1v) * c2v + cb2c;
      S += p;
      SX += p * __shfl(pjx, row, 32);
      SY += p * __shfl(pjy, row, 32);
    }
  }

  // ---- partial msg writeout (combine the two k-halves)
  msum += __shfl_xor(msum, 32);
  if (l < 32) ws[WS_MSG4 + ((node<<2) + part)*128 + 32*w + lo] = msum;

  // ---- partial coordinate sums
#pragma unroll
  for (int off = 32; off > 0; off >>= 1) {
    S  += __shfl_xor(S, off);
    SX += __shfl_xor(SX, off);
    SY += __shfl_xor(SY, off);
  }
  if (l == 0) { shred[w] = S; shred[4 + w] = SX; shred[8 + w] = SY; }
  __syncthreads();
  if (t == 0) {
    float* up = ws + WS_UPD + ((node<<2) + part)*4;
    up[0] = shred[0] + shred[1] + shred[2]  + shred[3];
    up[1] = shred[4] + shred[5] + shred[6]  + shred[7];
    up[2] = shred[8] + shred[9] + shred[10] + shred[11];
  }
}

// ---------------------------------------------------------------- K4
// Merge msg/upd parts; node MLP + residual + LN; pos/vel writeout.
__global__ __launch_bounds__(128)
void k4_node(const float* __restrict__ h, const float* __restrict__ pos,
             const float* __restrict__ vel, const float* __restrict__ ws,
             const float* __restrict__ nw1, const float* __restrict__ nb1,
             const float* __restrict__ nw2, const float* __restrict__ nb2,
             const float* __restrict__ lng, const float* __restrict__ lnb,
             float* __restrict__ out) {
  int node = blockIdx.x;
  int t = threadIdx.x;
  __shared__ float sh_in[256];
  __shared__ float sh_hid[HID];
  __shared__ float rbuf[4];

  const float* mbase = ws + WS_MSG4 + (node<<2)*128;
  sh_in[t]       = h[node*HID + t];
  sh_in[HID + t] = mbase[t] + mbase[128 + t] + mbase[256 + t] + mbase[384 + t];
  __syncthreads();

  float s = nb1[t];
#pragma unroll 4
  for (int k = 0; k < 256; ++k) s += sh_in[k] * nw1[k*HID + t];
  sh_hid[t] = silu_f(s);
  __syncthreads();

  float hn = nb2[t];
#pragma unroll 4
  for (int k = 0; k < HID; ++k) hn += sh_hid[k] * nw2[k*HID + t];
  float x = sh_in[t] + hn;

  float v1 = x, v2 = x*x;
#pragma unroll
  for (int off = 32; off > 0; off >>= 1) {
    v1 += __shfl_down(v1, off);
    v2 += __shfl_down(v2, off);
  }
  if ((t & 63) == 0) { rbuf[t>>6] = v1; rbuf[2 + (t>>6)] = v2; }
  __syncthreads();
  float mu  = (rbuf[0] + rbuf[1]) * (1.f/HID);
  float var = (rbuf[2] + rbuf[3]) * (1.f/HID) - mu*mu;
  float inv = 1.f / sqrtf(var + 1e-5f);
  out[node*HID + t] = (x - mu) * inv * lng[t] + lnb[t];

  if (t == 0) {
    const float* up = ws + WS_UPD + (node<<2)*4;
    float St  = up[0] + up[4] + up[8]  + up[12];
    float SXt = up[1] + up[5] + up[9]  + up[13];
    float SYt = up[2] + up[6] + up[10] + up[14];
    float pix = pos[node*2], piy = pos[node*2+1];
    float updx = pix*St - SXt, updy = piy*St - SYt;
    out[OUT_POS + node*2+0] = pix + updx;
    out[OUT_POS + node*2+1] = piy + updy;
    out[OUT_VEL + node*2+0] = vel[node*2+0] + 0.1f*updx;
    out[OUT_VEL + node*2+1] = vel[node*2+1] + 0.1f*updy;
  }
}

// ---------------------------------------------------------------- launch
extern "C" void kernel_launch(void* const* d_in, const int* in_sizes, int n_in,
                              void* d_out, int out_size, void* d_ws, size_t ws_size,
                              hipStream_t stream) {
  (void)in_sizes; (void)n_in; (void)out_size; (void)ws_size;
  const float* h   = (const float*)d_in[0];
  const float* pos = (const float*)d_in[1];
  const float* vel = (const float*)d_in[2];
  const float* ew1 = (const float*)d_in[3];
  const float* eb1 = (const float*)d_in[4];
  const float* ew2 = (const float*)d_in[5];
  const float* eb2 = (const float*)d_in[6];
  const float* cw1 = (const float*)d_in[7];
  const float* cb1 = (const float*)d_in[8];
  const float* cw2 = (const float*)d_in[9];
  const float* cb2 = (const float*)d_in[10];
  const float* nw1 = (const float*)d_in[11];
  const float* nb1 = (const float*)d_in[12];
  const float* nw2 = (const float*)d_in[13];
  const float* nb2 = (const float*)d_in[14];
  const float* lng = (const float*)d_in[15];
  const float* lnb = (const float*)d_in[16];
  float* out = (float*)d_out;
  float* ws  = (float*)d_ws;
  unsigned short* wsU = (unsigned short*)d_ws;

  hipLaunchKernelGGL(k0_prep, dim3(208), dim3(256), 0, stream, ew1, ew2, cw1, wsU);
  hipLaunchKernelGGL(k1_precompute, dim3(NNODE), dim3(256), 0, stream, h, ew1, eb1, ws);
  hipLaunchKernelGGL(k3_edge, dim3(NNODE*JSPLIT), dim3(256), 0, stream,
                     pos, eb2, cb1, cw2, cb2, ws);
  hipLaunchKernelGGL(k4_node, dim3(NNODE), dim3(128), 0, stream,
                     h, pos, vel, ws, nw1, nb1, nw2, nb2, lng, lnb, out);
}

// Round 6
// 353.612 us; speedup vs baseline: 1.4049x; 1.4049x over previous
//
#include <hip/hip_runtime.h>
#include <math.h>

#define HID 128
#define NN 512
#define NNODE 1024
#define CUTR 10.0f

// ---- ws layout, float offsets
#define WS_A    0            // [1024][256] fp32  (A_i + bias + const-angular row)
#define WS_MSG  262144       // [1024][128] fp32  msg_agg
// ---- ws layout, ushort offsets (ws viewed as unsigned short*)
#define SBMT_OFF 786432                  // BmT bf16 [2][256][512]  (c-major, j inner)
#define SE2T_OFF (SBMT_OFF + 262144)     // ew2^T bf16 [128][256]
#define SC1T_OFF (SE2T_OFF + 32768)      // cw1^T bf16 [128][128]
#define SW1G_OFF (SC1T_OFF + 16384)      // W1g^T bf16 [256][16]

// ---- out layout (float offsets)
#define OUT_POS 131072
#define OUT_VEL 133120

typedef __attribute__((ext_vector_type(8)))  short short8;
typedef __attribute__((ext_vector_type(4)))  unsigned short ushort4v;
typedef __attribute__((ext_vector_type(8)))  __bf16 bf16x8;
typedef __attribute__((ext_vector_type(16))) float float16;

__device__ __forceinline__ float silu_f(float x) {
  // x * v_rcp_f32(1+exp(-x)) — avoids the ~10-instr IEEE div sequence
  return x * __builtin_amdgcn_rcpf(1.f + __expf(-x));
}
__device__ __forceinline__ short f2bf(float x) {
  return __builtin_bit_cast(short, (__bf16)x);   // native v_cvt on gfx950 (RNE)
}
__device__ __forceinline__ float bf2f(unsigned short u) {
  union { unsigned u; float f; } v; v.u = ((unsigned)u) << 16;
  return v.f;
}
__device__ __forceinline__ bf16x8 as_bf(short8 s) {
  return __builtin_bit_cast(bf16x8, s);
}
__device__ __forceinline__ float16 zero16() {
  float16 z;
#pragma unroll
  for (int r = 0; r < 16; ++r) z[r] = 0.f;
  return z;
}

// ---------------------------------------------------------------- K0
// Transpose + bf16-convert weights: ew2^T, cw1^T, W1g^T (geometry rows of ew1).
__global__ __launch_bounds__(256)
void k0_prep(const float* __restrict__ ew1, const float* __restrict__ ew2,
             const float* __restrict__ cw1, unsigned short* __restrict__ wsU) {
  int idx = blockIdx.x * 256 + threadIdx.x;
  if (idx < 32768) {
    int c = idx >> 8, k = idx & 255;
    wsU[SE2T_OFF + c*256 + k] = (unsigned short)f2bf(ew2[k*HID + c]);
  } else if (idx < 49152) {
    int i2 = idx - 32768; int c = i2 >> 7, k = i2 & 127;
    wsU[SC1T_OFF + c*128 + k] = (unsigned short)f2bf(cw1[k*HID + c]);
  } else if (idx < 53248) {
    int i3 = idx - 49152; int c = i3 >> 4, f = i3 & 15;
    // f: 0..7 radial -> ew1 rows 256..263; 8..11 cos -> 265..268; 12..15 sin -> 269..272
    int row = (f < 8) ? (256 + f) : (257 + f);
    wsU[SW1G_OFF + c*16 + f] = (unsigned short)f2bf(ew1[row*256 + c]);
  }
}

// ---------------------------------------------------------------- K1
// A[n][c] = eb1[c] + ew1[264][c] + sum_k h[n][k]*ew1[k][c]   (fp32, [node][256])
// BmT[b][c][j] = bf16( sum_k h[b,j][k]*ew1[128+k][c] )
__global__ __launch_bounds__(256)
void k1_precompute(const float* __restrict__ h, const float* __restrict__ ew1,
                   const float* __restrict__ eb1, float* __restrict__ ws,
                   unsigned short* __restrict__ wsU) {
  int node = blockIdx.x;
  int c = threadIdx.x;
  __shared__ float sh_h[HID];
  if (c < HID) sh_h[c] = h[node*HID + c];
  __syncthreads();
  float a  = eb1[c] + ew1[264*256 + c];
  float bm = 0.f;
#pragma unroll 4
  for (int k = 0; k < HID; ++k) {
    float hv = sh_h[k];
    a  += hv * ew1[k*256 + c];
    bm += hv * ew1[(128+k)*256 + c];
  }
  ws[WS_A + node*256 + c] = a;
  int b = node >> 9, j = node & 511;
  wsU[SBMT_OFF + b*131072 + c*512 + j] = (unsigned short)f2bf(bm);
}

// ---------------------------------------------------------------- K3
// One block per (b,i); 4 waves; wave w owns output cols [32w,32w+32).
// Geometry inline. No min-waves bound (cliff: VGPR must stay <= 128 for
// 4 waves/SIMD; round 5's 132-VGPR build dropped to 3 and regressed 25%).
__global__ __launch_bounds__(256)
void k3_edge(const float* __restrict__ pos, const float* __restrict__ vel,
             const float* __restrict__ eb2, const float* __restrict__ cb1,
             const float* __restrict__ cw2, const float* __restrict__ cb2,
             float* __restrict__ ws, float* __restrict__ out) {
  const short* wsS = (const short*)ws;
  const unsigned short* wsU = (const unsigned short*)ws;
  __shared__ __align__(16) short shH[32*256];   // bf16, xor-swizzled 16B chunks
  __shared__ __align__(16) short shE[32*128];   // bf16, xor-swizzled 16B chunks
  __shared__ float shred[12];

  const int t = threadIdx.x;
  const int w = t >> 6, l = t & 63, lo = l & 31, hl = l >> 5, hl4 = hl * 4;
  const int node = blockIdx.x;
  const int b = node >> 9;
  const int bN = b * NN;

  // persistent B-fragments: cw1^T (8 MFMA steps, reused 16x) + W1g^T (2 halves)
  bf16x8 wb2[8];
  {
    const short* p = wsS + SC1T_OFF + (32*w + lo)*128 + hl*8;
#pragma unroll
    for (int s = 0; s < 8; ++s) wb2[s] = as_bf(*(const short8*)(p + s*16));
  }
  const bf16x8 wg0 = as_bf(*(const short8*)(wsS + SW1G_OFF + (64*w + lo)*16 + hl*8));
  const bf16x8 wg1 = as_bf(*(const short8*)(wsS + SW1G_OFF + (64*w + 32 + lo)*16 + hl*8));

  const float a0   = ws[WS_A + node*256 + 64*w + lo];
  const float a1   = ws[WS_A + node*256 + 64*w + 32 + lo];
  const float ebv  = eb2[32*w + lo];
  const float cb1v = cb1[32*w + lo];
  const float c2v  = cw2[32*w + lo];
  const float cb2c = cb2[0] * (1.f/128.f);
  const float pix  = pos[node*2], piy = pos[node*2+1];

  float msum = 0.f;
  float S = 0.f, SX = 0.f, SY = 0.f;

  for (int jb = 0; jb < NN; jb += 32) {
    // ---- inline geometry for j = jb + lo
    const int jn = bN + jb + lo;
    const float pjx = pos[2*jn], pjy = pos[2*jn+1];
    const float dx = pix - pjx, dy = piy - pjy;
    const float d = sqrtf(dx*dx + dy*dy);
    const float cutv = (d < CUTR) ? 0.5f*(__cosf((float)M_PI*(1.f/CUTR)*d) + 1.f) : 0.f;
    short8 gs;
    if (hl == 0) {
      // radial features 0..7
#pragma unroll
      for (int k = 0; k < 8; ++k) {
        float ctr = (CUTR * (float)k) / 7.0f;
        float tt = (d - ctr) * 0.8f;
        gs[k] = f2bf(__expf(-tt*tt));
      }
    } else {
      // angular features: cos(m th), sin(m th) via recurrence on (dx/d, dy/d)
      float invd = __builtin_amdgcn_rcpf(d + 1e-8f);
      float c1 = dx * invd, s1 = dy * invd;
      if (d == 0.f) { c1 = 1.f; s1 = 0.f; }   // matches atan2(0,0)=0
      float c2 = c1*c1 - s1*s1, s2 = 2.f*s1*c1;
      float c3 = c2*c1 - s2*s1, s3 = s2*c1 + c2*s1;
      float c4 = c3*c1 - s3*s1, s4 = s3*c1 + c3*s1;
      gs[0]=f2bf(c1); gs[1]=f2bf(c2); gs[2]=f2bf(c3); gs[3]=f2bf(c4);
      gs[4]=f2bf(s1); gs[5]=f2bf(s2); gs[6]=f2bf(s3); gs[7]=f2bf(s4);
    }
    const bf16x8 gf = as_bf(gs);

    // ---- phase 1: Hpre = G @ W1g + (A_i + Bm_j); silu -> shH (bf16, swizzled)
#pragma unroll
    for (int ct = 0; ct < 2; ++ct) {
      const int colg = 64*w + 32*ct + lo;
      const float av = ct ? a1 : a0;
      const unsigned short* bt = wsU + SBMT_OFF + b*131072 + colg*512 + jb + hl4;
      float16 ci;
#pragma unroll
      for (int g = 0; g < 4; ++g) {
        ushort4v v4 = *(const ushort4v*)(bt + 8*g);
        ci[4*g+0] = bf2f(v4[0]) + av;
        ci[4*g+1] = bf2f(v4[1]) + av;
        ci[4*g+2] = bf2f(v4[2]) + av;
        ci[4*g+3] = bf2f(v4[3]) + av;
      }
      float16 hp = __builtin_amdgcn_mfma_f32_32x32x16_bf16(gf, ct ? wg1 : wg0, ci, 0, 0, 0);
      const int ck = colg >> 3;
#pragma unroll
      for (int r = 0; r < 16; ++r) {
        int row = (r&3) + 8*(r>>2) + hl4;
        shH[row*256 + (((ck ^ row) & 31) << 3) + (colg & 7)] = f2bf(silu_f(hp[r]));
      }
    }
    __syncthreads();

    // ---- GEMM1: e = H @ ew2 (K=256), weights streamed from L1/L2.
    // unroll 4: cap in-flight weight vectors (full unroll hoisted 16x4 regs).
    float16 acc1 = zero16();
    {
      const short* wp1 = wsS + SE2T_OFF + (32*w + lo)*256 + hl*8;
#pragma unroll 4
      for (int s = 0; s < 16; ++s) {
        bf16x8 wv = as_bf(*(const short8*)(wp1 + 16*s));
        const int ck = 2*s + hl;
        bf16x8 af = as_bf(*(const short8*)(shH + lo*256 + (((ck ^ lo) & 31) << 3)));
        acc1 = __builtin_amdgcn_mfma_f32_32x32x16_bf16(af, wv, acc1, 0, 0, 0);
      }
    }
    // epilogue 1: +bias, *cutoff (shfl), msg acc, bf16 -> shE
    const int kE = 32*w + lo;
    const int ckE = kE >> 3;
#pragma unroll
    for (int r = 0; r < 16; ++r) {
      int row = (r&3) + 8*(r>>2) + hl4;
      float cr = __shfl(cutv, row, 32);
      float ev = (acc1[r] + ebv) * cr;
      msum += ev;
      shE[row*128 + (((ckE ^ (row & 15)) & 15) << 3) + (kE & 7)] = f2bf(ev);
    }
    __syncthreads();

    // ---- GEMM2: c1 = E @ cw1 (K=128)
    float16 acc2 = zero16();
#pragma unroll
    for (int s = 0; s < 8; ++s) {
      const int ck = 2*s + hl;
      bf16x8 af = as_bf(*(const short8*)(shE + lo*128 + (((ck ^ (lo & 15)) & 15) << 3)));
      acc2 = __builtin_amdgcn_mfma_f32_32x32x16_bf16(af, wb2[s], acc2, 0, 0, 0);
    }
    // epilogue 2: silu, *cw2, accumulate S / SX / SY (upd = pos_i*S - S*pos_j)
#pragma unroll
    for (int r = 0; r < 16; ++r) {
      int row = (r&3) + 8*(r>>2) + hl4;
      float p = silu_f(acc2[r] + cb1v) * c2v + cb2c;
      S += p;
      SX += p * __shfl(pjx, row, 32);
      SY += p * __shfl(pjy, row, 32);
    }
  }

  // ---- msg writeout (combine the two k-halves)
  msum += __shfl_xor(msum, 32);
  if (l < 32) ws[WS_MSG + node*128 + 32*w + lo] = msum;

  // ---- coordinate update reduction
#pragma unroll
  for (int off = 32; off > 0; off >>= 1) {
    S  += __shfl_xor(S, off);
    SX += __shfl_xor(SX, off);
    SY += __shfl_xor(SY, off);
  }
  if (l == 0) { shred[w] = S; shred[4 + w] = SX; shred[8 + w] = SY; }
  __syncthreads();
  if (t == 0) {
    float St  = shred[0] + shred[1] + shred[2]  + shred[3];
    float SXt = shred[4] + shred[5] + shred[6]  + shred[7];
    float SYt = shred[8] + shred[9] + shred[10] + shred[11];
    float updx = pix*St - SXt, updy = piy*St - SYt;
    out[OUT_POS + node*2+0] = pix + updx;
    out[OUT_POS + node*2+1] = piy + updy;
    out[OUT_VEL + node*2+0] = vel[node*2+0] + 0.1f*updx;
    out[OUT_VEL + node*2+1] = vel[node*2+1] + 0.1f*updy;
  }
}

// ---------------------------------------------------------------- K4
__global__ __launch_bounds__(128)
void k4_node(const float* __restrict__ h, const float* __restrict__ ws,
             const float* __restrict__ nw1, const float* __restrict__ nb1,
             const float* __restrict__ nw2, const float* __restrict__ nb2,
             const float* __restrict__ lng, const float* __restrict__ lnb,
             float* __restrict__ out) {
  int node = blockIdx.x;
  int t = threadIdx.x;
  __shared__ float sh_in[256];
  __shared__ float sh_hid[HID];
  __shared__ float rbuf[4];

  sh_in[t]       = h[node*HID + t];
  sh_in[HID + t] = ws[WS_MSG + (size_t)node*HID + t];
  __syncthreads();

  float s = nb1[t];
#pragma unroll 4
  for (int k = 0; k < 256; ++k) s += sh_in[k] * nw1[k*HID + t];
  sh_hid[t] = silu_f(s);
  __syncthreads();

  float hn = nb2[t];
#pragma unroll 4
  for (int k = 0; k < HID; ++k) hn += sh_hid[k] * nw2[k*HID + t];
  float x = sh_in[t] + hn;

  float v1 = x, v2 = x*x;
#pragma unroll
  for (int off = 32; off > 0; off >>= 1) {
    v1 += __shfl_down(v1, off);
    v2 += __shfl_down(v2, off);
  }
  if ((t & 63) == 0) { rbuf[t>>6] = v1; rbuf[2 + (t>>6)] = v2; }
  __syncthreads();
  float mu  = (rbuf[0] + rbuf[1]) * (1.f/HID);
  float var = (rbuf[2] + rbuf[3]) * (1.f/HID) - mu*mu;
  float inv = 1.f / sqrtf(var + 1e-5f);
  out[node*HID + t] = (x - mu) * inv * lng[t] + lnb[t];
}

// ---------------------------------------------------------------- launch
extern "C" void kernel_launch(void* const* d_in, const int* in_sizes, int n_in,
                              void* d_out, int out_size, void* d_ws, size_t ws_size,
                              hipStream_t stream) {
  (void)in_sizes; (void)n_in; (void)out_size; (void)ws_size;
  const float* h   = (const float*)d_in[0];
  const float* pos = (const float*)d_in[1];
  const float* vel = (const float*)d_in[2];
  const float* ew1 = (const float*)d_in[3];
  const float* eb1 = (const float*)d_in[4];
  const float* ew2 = (const float*)d_in[5];
  const float* eb2 = (const float*)d_in[6];
  const float* cw1 = (const float*)d_in[7];
  const float* cb1 = (const float*)d_in[8];
  const float* cw2 = (const float*)d_in[9];
  const float* cb2 = (const float*)d_in[10];
  const float* nw1 = (const float*)d_in[11];
  const float* nb1 = (const float*)d_in[12];
  const float* nw2 = (const float*)d_in[13];
  const float* nb2 = (const float*)d_in[14];
  const float* lng = (const float*)d_in[15];
  const float* lnb = (const float*)d_in[16];
  float* out = (float*)d_out;
  float* ws  = (float*)d_ws;
  unsigned short* wsU = (unsigned short*)d_ws;

  hipLaunchKernelGGL(k0_prep, dim3(208), dim3(256), 0, stream, ew1, ew2, cw1, wsU);
  hipLaunchKernelGGL(k1_precompute, dim3(NNODE), dim3(256), 0, stream, h, ew1, eb1, ws, wsU);
  hipLaunchKernelGGL(k3_edge, dim3(NNODE), dim3(256), 0, stream,
                     pos, vel, eb2, cb1, cw2, cb2, ws, out);
  hipLaunchKernelGGL(k4_node, dim3(NNODE), dim3(128), 0, stream,
                     h, ws, nw1, nb1, nw2, nb2, lng, lnb, out);
}